// Round 8
// baseline (1787.338 us; speedup 1.0000x reference)
//
#include <hip/hip_runtime.h>

#define N_NODES 50000
#define N_EDGES 1600000
#define HDIM 128
#define N_CLASSES 40
#define N_LAYERS 8
#define CAP 160                 // max stored in-degree; Poisson(32) => P(>160) ~ 0

#define BUILD_BLOCKS 1563       // ceil(1.6M/4/256)
#define CONV_BLOCKS  3125       // 50000*128/8/256
#define PREP_BLOCKS   600       // 9*16384/256 (=576) + 48*128/256 (=24)

// h/x/p/hs are FEATURE-QUARTERED: 4 blocks of [N_NODES][32 feats] (64B/node/quarter).
// Aggregation runs quarter-major: hot set 3.2MB fits the 4MB per-XCD L2.
#define QF16  ((size_t)N_NODES * 32)   // f16 elems per quarter

typedef _Float16 f16;
typedef _Float16 f16x2 __attribute__((ext_vector_type(2)));
typedef _Float16 f16x4 __attribute__((ext_vector_type(4)));
typedef _Float16 f16x8 __attribute__((ext_vector_type(8)));
typedef float f32x4 __attribute__((ext_vector_type(4)));
typedef int i32x4 __attribute__((ext_vector_type(4)));

__device__ __forceinline__ int clamp_idx(int v) {
    v = v < 0 ? 0 : v;
    return v >= N_NODES ? N_NODES - 1 : v;
}

// ---------------- fused setup: CSR build (u16 slots) + x->fp16(quartered) + weight prep ----------------

__global__ __launch_bounds__(256) void setup_kernel(
        const int* __restrict__ ei, const float* __restrict__ x,
        const float* __restrict__ W_in, const float* __restrict__ gcn_W,
        const float* __restrict__ W_out,
        int* __restrict__ deg_cnt, int* __restrict__ col_cnt,
        unsigned short* __restrict__ e_slot,
        f16* __restrict__ x16, f16* __restrict__ wt, f16* __restrict__ wot) {
    int b = blockIdx.x;
    if (b < BUILD_BLOCKS) {
        int t = b * 256 + threadIdx.x;          // one int4 = 4 edges
        if (t < N_EDGES / 4) {
            i32x4 r4 = ((const i32x4*)ei)[t];
            i32x4 c4 = ((const i32x4*)(ei + N_EDGES))[t];
#pragma unroll
            for (int i = 0; i < 4; ++i) {
                int r = clamp_idx(r4[i]);
                int c = clamp_idx(c4[i]);
                if (r != c) {
                    atomicAdd(&deg_cnt[r], 1);               // fire-and-forget
                    int s = atomicAdd(&col_cnt[c], 1);       // slot
                    if (s < CAP) e_slot[(size_t)c * CAP + s] = (unsigned short)r;
                }
            }
        }
    } else if (b < BUILD_BLOCKS + CONV_BLOCKS) {
        int i = (b - BUILD_BLOCKS) * 256 + threadIdx.x;      // group of 8 floats
        if (i < N_NODES * HDIM / 8) {
            int node = i >> 4, f8 = i & 15;
            const float4* xs = (const float4*)x;
            float4 v0 = xs[2 * i], v1 = xs[2 * i + 1];
            f16x8 o;
            o[0] = (f16)v0.x; o[1] = (f16)v0.y; o[2] = (f16)v0.z; o[3] = (f16)v0.w;
            o[4] = (f16)v1.x; o[5] = (f16)v1.y; o[6] = (f16)v1.z; o[7] = (f16)v1.w;
            int quarter = f8 >> 2;
            ((f16x8*)x16)[(size_t)quarter * N_NODES * 4 + (size_t)node * 4 + (f8 & 3)] = o;
        }
    } else {
        int idx = (b - BUILD_BLOCKS - CONV_BLOCKS) * 256 + threadIdx.x;
        if (idx < 9 * HDIM * HDIM) {
            // W_in + gcn_W -> fp16, transposed: wt[mat][n][k]
            int mat = idx >> 14;
            int rem = idx & 16383;
            int k = rem >> 7, n = rem & 127;
            float v = (mat == 0) ? W_in[rem] : gcn_W[(mat - 1) * 16384 + rem];
            wt[mat * 16384 + n * 128 + k] = (f16)v;
        } else {
            int j = idx - 9 * HDIM * HDIM;                   // 0..6143
            if (j < 48 * 128) {
                int n = j >> 7, k = j & 127;                 // wot[n][k], pad n>=40
                wot[n * 128 + k] = (n < N_CLASSES) ? (f16)W_out[k * N_CLASSES + n] : (f16)0.f;
            }
        }
    }
}

// per-node constants: combo = {dis, 0.8*dis, (0.8/deg+0.1)*sqrt(deg), sqrt(deg)}
__global__ void combo_kernel(const int* __restrict__ deg_cnt, float4* __restrict__ combo) {
    int i = blockIdx.x * blockDim.x + threadIdx.x;
    if (i >= N_NODES) return;
    float d = (float)(deg_cnt[i] + 1);   // includes self loop, >= 1
    float dis = rsqrtf(d);
    float g = sqrtf(d);                  // 1/dis
    combo[i] = make_float4(dis, 0.8f * dis, (0.8f / d + 0.1f) * g, g);
}

// ---------------- aggregation + residual combine (quartered, L2-resident) ----------------
// wave per (node, quarter); grid is quarter-major. Group g=lane>>4 owns one of 4
// edges in the pack; lane m=lane&15 owns f16x2 of the 64B quarter-row. Slot list
// read as cached wave-uniform ushort4 (no nontemporal — that was round 6's bug).
// hs rows pre-scaled by dis[r]: inner loop is a pure masked sum.

__global__ __launch_bounds__(256) void agg_combine(
        const f16* __restrict__ hs, const f16* __restrict__ h0_16,
        const int* __restrict__ col_cnt, const unsigned short* __restrict__ e_slot,
        const float4* __restrict__ combo, f16* __restrict__ p16) {
    int gw = blockIdx.x * 4 + (threadIdx.x >> 6);
    int q = gw / N_NODES;                 // 0..3, quarter-major dispatch
    int w = gw - q * N_NODES;
    int lane = threadIdx.x & 63;
    int g = lane >> 4, m = lane & 15;
    int cnt = col_cnt[w]; if (cnt > CAP) cnt = CAP;
    const f16x2* hq = (const f16x2*)(hs + (size_t)q * QF16);   // [node][16] f16x2
    const unsigned short* slots = e_slot + (size_t)w * CAP;
    float a0 = 0.f, a1 = 0.f;
#pragma unroll 2
    for (int e = 0; e < cnt; e += 4) {
        ushort4 s4 = *(const ushort4*)(slots + e);      // wave-uniform cached 8B
        int r = (g == 0) ? s4.x : (g == 1) ? s4.y : (g == 2) ? s4.z : s4.w;
        float msk = (e + g < cnt) ? 1.f : 0.f;
        f16x2 v = hq[(size_t)r * 16 + m];
        a0 += msk * (float)v[0];
        a1 += msk * (float)v[1];
    }
    a0 += __shfl_xor(a0, 16); a1 += __shfl_xor(a1, 16);
    a0 += __shfl_xor(a0, 32); a1 += __shfl_xor(a1, 32);

    if (g == 0) {
        float4 cb = combo[w];
        f16x2 hw = hq[(size_t)w * 16 + m];
        f16x2 h0v = ((const f16x2*)(h0_16 + (size_t)q * QF16))[(size_t)w * 16 + m];
        float px = cb.y * a0 + cb.z * (float)hw[0] + 0.1f * (float)h0v[0];
        float py = cb.y * a1 + cb.z * (float)hw[1] + 0.1f * (float)h0v[1];
        f16x2 o; o[0] = (f16)px; o[1] = (f16)py;
        ((f16x2*)(p16 + (size_t)q * QF16))[(size_t)w * 16 + m] = o;
    }
}

// ---------------- fp16 MFMA GEMM (quartered A/out): act(A @ W) -> hs (+h0 for mode 0) ----------------
// mode 0: v = relu(acc + b); h0_out = v; hs_out = dis*v
// mode 1: v = max(acc, sb);  hs_out = dis*v
#define WT_OFF 16384

__global__ __launch_bounds__(256, 2) void gemm_mfma(
        const f16* __restrict__ A, const f16* __restrict__ Wt,
        const float* __restrict__ bvec, const float4* __restrict__ combo,
        f16* __restrict__ hs_out, f16* __restrict__ h0_out, int mode) {
    __shared__ uint4 smem4[3072];                // 48 KiB: A 16K | Wt 32K
    char* smem = (char*)smem4;
    int tid = threadIdx.x;
    int r0 = blockIdx.x * 64;

    const uint4* Asrc = (const uint4*)A;         // quarter stride = N_NODES*4 uint4
    for (int c = tid; c < 1024; c += 256) {
        int row = c >> 4, s = c & 15;
        int grow = r0 + row; if (grow >= N_NODES) grow = N_NODES - 1;
        int quarter = s >> 2;
        uint4 v = Asrc[(size_t)quarter * N_NODES * 4 + (size_t)grow * 4 + (s & 3)];
        *(uint4*)&smem[row * 256 + ((s * 16) ^ ((row & 7) << 4))] = v;
    }
    const uint4* Wsrc = (const uint4*)Wt;
    for (int c = tid; c < 2048; c += 256) {
        int n = c >> 4, s = c & 15;
        uint4 v = Wsrc[n * 16 + s];
        *(uint4*)&smem[WT_OFF + n * 256 + ((s * 16) ^ ((n & 7) << 4))] = v;
    }
    __syncthreads();

    int l = tid & 63, w = tid >> 6;
    int wr = w >> 1, wc = w & 1;
    int lg = l >> 4, lm = l & 15;

    union F8 { f16x8 v8; struct { f16x4 lo, hi; } p; };
    f32x4 acc[2][4];
#pragma unroll
    for (int m = 0; m < 2; ++m)
#pragma unroll
        for (int j = 0; j < 4; ++j) acc[m][j] = (f32x4){0.f, 0.f, 0.f, 0.f};

#pragma unroll
    for (int kk = 0; kk < 4; ++kk) {
        int boff = kk * 64 + lg * 8;
        F8 a[2], b[4];
#pragma unroll
        for (int m = 0; m < 2; ++m) {
            int row = wr * 32 + m * 16 + lm;
            int swz = (row & 7) << 4;
            int rb = row * 256;
            a[m].p.lo = *(const f16x4*)&smem[rb + (boff ^ swz)];
            a[m].p.hi = *(const f16x4*)&smem[rb + ((boff + 32) ^ swz)];
        }
#pragma unroll
        for (int j = 0; j < 4; ++j) {
            int n = wc * 64 + j * 16 + lm;
            int swz = (n & 7) << 4;
            int nb = WT_OFF + n * 256;
            b[j].p.lo = *(const f16x4*)&smem[nb + (boff ^ swz)];
            b[j].p.hi = *(const f16x4*)&smem[nb + ((boff + 32) ^ swz)];
        }
#pragma unroll
        for (int m = 0; m < 2; ++m)
#pragma unroll
            for (int j = 0; j < 4; ++j)
                acc[m][j] = __builtin_amdgcn_mfma_f32_16x16x32_f16(a[m].v8, b[j].v8, acc[m][j], 0, 0, 0);
    }

#pragma unroll
    for (int m = 0; m < 2; ++m) {
#pragma unroll
        for (int r = 0; r < 4; ++r) {
            int row = r0 + wr * 32 + m * 16 + lg * 4 + r;
            if (row < N_NODES) {
                float dis = combo[row].x;
#pragma unroll
                for (int j = 0; j < 4; ++j) {
                    int col = wc * 64 + j * 16 + lm;
                    float bias = bvec[col];
                    float v = acc[m][j][r];
                    v = mode ? fmaxf(v, bias) : fmaxf(v + bias, 0.f);
                    int quarter = col >> 5, cm = col & 31;
                    if (mode == 0)
                        h0_out[(size_t)quarter * QF16 + (size_t)row * 32 + cm] = (f16)v;
                    hs_out[(size_t)quarter * QF16 + (size_t)row * 32 + cm] = (f16)(dis * v);
                }
            }
        }
    }
}

// ---------------- output layer via MFMA: out = (hs/dis) @ W_out + b_out ----------------
#define WOT_OFF 16384   // A tile 64*256B

__global__ __launch_bounds__(256) void out_mfma(
        const f16* __restrict__ A, const f16* __restrict__ Wot,
        const float* __restrict__ bo, const float4* __restrict__ combo,
        float* __restrict__ out) {
    __shared__ uint4 smem4[1792];                // 28 KiB: A 16K | Wot 12K
    char* smem = (char*)smem4;
    int tid = threadIdx.x;
    int r0 = blockIdx.x * 64;

    const uint4* Asrc = (const uint4*)A;
    for (int c = tid; c < 1024; c += 256) {
        int row = c >> 4, s = c & 15;
        int grow = r0 + row; if (grow >= N_NODES) grow = N_NODES - 1;
        int quarter = s >> 2;
        uint4 v = Asrc[(size_t)quarter * N_NODES * 4 + (size_t)grow * 4 + (s & 3)];
        *(uint4*)&smem[row * 256 + ((s * 16) ^ ((row & 7) << 4))] = v;
    }
    const uint4* Wsrc = (const uint4*)Wot;
    for (int c = tid; c < 768; c += 256) {
        int n = c >> 4, s = c & 15;
        uint4 v = Wsrc[n * 16 + s];
        *(uint4*)&smem[WOT_OFF + n * 256 + ((s * 16) ^ ((n & 7) << 4))] = v;
    }
    __syncthreads();

    int l = tid & 63, w = tid >> 6;
    int lg = l >> 4, lm = l & 15;

    union F8 { f16x8 v8; struct { f16x4 lo, hi; } p; };
    f32x4 acc[3];
#pragma unroll
    for (int j = 0; j < 3; ++j) acc[j] = (f32x4){0.f, 0.f, 0.f, 0.f};

#pragma unroll
    for (int kk = 0; kk < 4; ++kk) {
        int boff = kk * 64 + lg * 8;
        F8 a, b[3];
        int row = w * 16 + lm;
        int swz = (row & 7) << 4;
        int rb = row * 256;
        a.p.lo = *(const f16x4*)&smem[rb + (boff ^ swz)];
        a.p.hi = *(const f16x4*)&smem[rb + ((boff + 32) ^ swz)];
#pragma unroll
        for (int j = 0; j < 3; ++j) {
            int n = j * 16 + lm;
            int swz2 = (n & 7) << 4;
            int nb = WOT_OFF + n * 256;
            b[j].p.lo = *(const f16x4*)&smem[nb + (boff ^ swz2)];
            b[j].p.hi = *(const f16x4*)&smem[nb + ((boff + 32) ^ swz2)];
        }
#pragma unroll
        for (int j = 0; j < 3; ++j)
            acc[j] = __builtin_amdgcn_mfma_f32_16x16x32_f16(a.v8, b[j].v8, acc[j], 0, 0, 0);
    }

#pragma unroll
    for (int r = 0; r < 4; ++r) {
        int row = r0 + w * 16 + lg * 4 + r;
        if (row < N_NODES) {
            float g2 = combo[row].w;      // 1/dis: un-scale the hs row
#pragma unroll
            for (int j = 0; j < 3; ++j) {
                int col = j * 16 + lm;
                if (col < N_CLASSES)
                    out[(size_t)row * N_CLASSES + col] = g2 * acc[j][r] + bo[col];
            }
        }
    }
}

// ---------------- launch ----------------

extern "C" void kernel_launch(void* const* d_in, const int* in_sizes, int n_in,
                              void* d_out, int out_size, void* d_ws, size_t ws_size,
                              hipStream_t stream) {
    const float* x       = (const float*)d_in[0];
    const int*   ei      = (const int*)d_in[1];
    const float* W_in    = (const float*)d_in[2];
    const float* b_in    = (const float*)d_in[3];
    const float* gcn_W   = (const float*)d_in[4];
    const float* srelu_b = (const float*)d_in[5];
    const float* W_out   = (const float*)d_in[6];
    const float* b_out   = (const float*)d_in[7];
    float* outp = (float*)d_out;

    char* ws = (char*)d_ws;
    size_t off = 0;
    auto alloc = [&](size_t bytes) -> void* {
        void* p = ws + off;
        off += (bytes + 255) & ~(size_t)255;
        return p;
    };
    int*    deg_cnt = (int*)alloc((size_t)N_NODES * 4);
    int*    col_cnt = (int*)alloc((size_t)N_NODES * 4);
    float4* combo   = (float4*)alloc((size_t)N_NODES * 16);
    unsigned short* e_slot = (unsigned short*)alloc((size_t)N_NODES * CAP * 2);
    f16*    wt16    = (f16*)alloc((size_t)9 * HDIM * HDIM * 2);
    f16*    wot16   = (f16*)alloc((size_t)48 * HDIM * 2);
    f16*    x16     = (f16*)alloc((size_t)N_NODES * HDIM * 2);
    f16*    h0_16   = (f16*)alloc((size_t)N_NODES * HDIM * 2);
    f16*    hs0     = (f16*)alloc((size_t)N_NODES * HDIM * 2);
    f16*    hsA     = (f16*)alloc((size_t)N_NODES * HDIM * 2);
    f16*    hsB     = (f16*)alloc((size_t)N_NODES * HDIM * 2);
    f16*    p16     = (f16*)alloc((size_t)N_NODES * HDIM * 2);

    hipMemsetAsync(deg_cnt, 0, (size_t)N_NODES * 4, stream);
    hipMemsetAsync(col_cnt, 0, (size_t)N_NODES * 4, stream);

    setup_kernel<<<BUILD_BLOCKS + CONV_BLOCKS + PREP_BLOCKS, 256, 0, stream>>>(
        ei, x, W_in, gcn_W, W_out, deg_cnt, col_cnt, e_slot, x16, wt16, wot16);
    combo_kernel<<<(N_NODES + 255) / 256, 256, 0, stream>>>(deg_cnt, combo);

    // input layer: h0 = relu(x @ W_in + b_in); hs0 = dis*h0
    gemm_mfma<<<(N_NODES + 63) / 64, 256, 0, stream>>>(
        x16, wt16, b_in, combo, hs0, h0_16, 0);

    const f16* hcur = hs0;
    for (int l = 0; l < N_LAYERS; ++l) {
        f16* hnext = (l & 1) ? hsB : hsA;
        agg_combine<<<N_NODES, 256, 0, stream>>>(      // 4 quarters x 50000 waves
            hcur, h0_16, col_cnt, e_slot, combo, p16);
        gemm_mfma<<<(N_NODES + 63) / 64, 256, 0, stream>>>(
            p16, wt16 + (size_t)(l + 1) * HDIM * HDIM,
            srelu_b + (size_t)l * HDIM, combo, hnext, nullptr, 1);
        hcur = hnext;
    }

    out_mfma<<<(N_NODES + 63) / 64, 256, 0, stream>>>(hcur, wot16, b_out, combo, outp);
}

// Round 9
// 894.261 us; speedup vs baseline: 1.9987x; 1.9987x over previous
//
#include <hip/hip_runtime.h>

#define N_NODES 50000
#define N_EDGES 1600000
#define HDIM 128
#define N_CLASSES 40
#define N_LAYERS 8
#define CAP 160                 // max stored in-degree; Poisson(32) => P(>160) ~ 0

#define BUILD_BLOCKS 1563       // ceil(1.6M/4/256)
#define CONV_BLOCKS  3125       // 50000*128/8/256
#define PREP_BLOCKS   600       // 9*16384/256 (=576) + 48*128/256 (=24)

typedef _Float16 f16;
typedef _Float16 f16x2 __attribute__((ext_vector_type(2)));
typedef _Float16 f16x4 __attribute__((ext_vector_type(4)));
typedef _Float16 f16x8 __attribute__((ext_vector_type(8)));
typedef float f32x4 __attribute__((ext_vector_type(4)));
typedef int i32x4 __attribute__((ext_vector_type(4)));

__device__ __forceinline__ int clamp_idx(int v) {
    v = v < 0 ? 0 : v;
    return v >= N_NODES ? N_NODES - 1 : v;
}

// ---------------- fused setup: CSR build (u16 slots) + x->fp16 + weight prep ----------------

__global__ __launch_bounds__(256) void setup_kernel(
        const int* __restrict__ ei, const float* __restrict__ x,
        const float* __restrict__ W_in, const float* __restrict__ gcn_W,
        const float* __restrict__ W_out,
        int* __restrict__ deg_cnt, int* __restrict__ col_cnt,
        unsigned short* __restrict__ e_slot,
        f16* __restrict__ x16, f16* __restrict__ wt, f16* __restrict__ wot) {
    int b = blockIdx.x;
    if (b < BUILD_BLOCKS) {
        int t = b * 256 + threadIdx.x;          // one int4 = 4 edges
        if (t < N_EDGES / 4) {
            i32x4 r4 = ((const i32x4*)ei)[t];
            i32x4 c4 = ((const i32x4*)(ei + N_EDGES))[t];
#pragma unroll
            for (int i = 0; i < 4; ++i) {
                int r = clamp_idx(r4[i]);
                int c = clamp_idx(c4[i]);
                if (r != c) {
                    atomicAdd(&deg_cnt[r], 1);               // fire-and-forget
                    int s = atomicAdd(&col_cnt[c], 1);       // slot
                    if (s < CAP) e_slot[(size_t)c * CAP + s] = (unsigned short)r;
                }
            }
        }
    } else if (b < BUILD_BLOCKS + CONV_BLOCKS) {
        int i = (b - BUILD_BLOCKS) * 256 + threadIdx.x;      // group of 8 floats
        if (i < N_NODES * HDIM / 8) {
            const float4* xs = (const float4*)x;
            float4 v0 = xs[2 * i], v1 = xs[2 * i + 1];
            f16x8 o;
            o[0] = (f16)v0.x; o[1] = (f16)v0.y; o[2] = (f16)v0.z; o[3] = (f16)v0.w;
            o[4] = (f16)v1.x; o[5] = (f16)v1.y; o[6] = (f16)v1.z; o[7] = (f16)v1.w;
            ((f16x8*)x16)[i] = o;
        }
    } else {
        int idx = (b - BUILD_BLOCKS - CONV_BLOCKS) * 256 + threadIdx.x;
        if (idx < 9 * HDIM * HDIM) {
            // W_in + gcn_W -> fp16, transposed: wt[mat][n][k]
            int mat = idx >> 14;
            int rem = idx & 16383;
            int k = rem >> 7, n = rem & 127;
            float v = (mat == 0) ? W_in[rem] : gcn_W[(mat - 1) * 16384 + rem];
            wt[mat * 16384 + n * 128 + k] = (f16)v;
        } else {
            int j = idx - 9 * HDIM * HDIM;                   // 0..6143
            if (j < 48 * 128) {
                int n = j >> 7, k = j & 127;                 // wot[n][k], pad n>=40
                wot[n * 128 + k] = (n < N_CLASSES) ? (f16)W_out[k * N_CLASSES + n] : (f16)0.f;
            }
        }
    }
}

// per-node constants: combo = {dis, 0.8*dis, (0.8/deg+0.1)*sqrt(deg), sqrt(deg)}
__global__ void combo_kernel(const int* __restrict__ deg_cnt, float4* __restrict__ combo) {
    int i = blockIdx.x * blockDim.x + threadIdx.x;
    if (i >= N_NODES) return;
    float d = (float)(deg_cnt[i] + 1);   // includes self loop, >= 1
    float dis = rsqrtf(d);
    float g = sqrtf(d);                  // 1/dis
    combo[i] = make_float4(dis, 0.8f * dis, (0.8f / d + 0.1f) * g, g);
}

// ---------------- aggregation + residual combine ----------------
// One wave per node. 16 lanes per edge, f16x8 (16B) per lane: ONE gather
// instruction covers 4 edges' full 256B rows. 8 edges in flight (paired packs).
// hs rows pre-scaled by dis[r]: pure masked sum; cross-group shfl reduce once.
// p[w] = 0.8*dis[w]*S + beta*hs[w] + 0.1*h0[w]

__global__ __launch_bounds__(256) void agg_combine(
        const f16* __restrict__ hs, const f16* __restrict__ h0_16,
        const int* __restrict__ col_cnt, const unsigned short* __restrict__ e_slot,
        const float4* __restrict__ combo, f16* __restrict__ p16) {
    int w = (blockIdx.x * blockDim.x + threadIdx.x) >> 6;
    int lane = threadIdx.x & 63;
    if (w >= N_NODES) return;
    int cnt = col_cnt[w]; if (cnt > CAP) cnt = CAP;
    int g = lane >> 4, m = lane & 15;
    const f16x8* hp = (const f16x8*)hs;                 // row = node*16 + m (16B units)
    const unsigned short* slots = e_slot + (size_t)w * CAP;
    float acc[8];
#pragma unroll
    for (int c = 0; c < 8; ++c) acc[c] = 0.f;

    auto pack = [&](int E) {
        ushort4 s4 = *(const ushort4*)(slots + E);      // wave-uniform cached 8B
        int r = (g == 0) ? s4.x : (g == 1) ? s4.y : (g == 2) ? s4.z : s4.w;
        r = (r < N_NODES) ? r : 0;                      // tail slots hold poison
        float msk = (E + g < cnt) ? 1.f : 0.f;
        f16x8 v = hp[(size_t)r * 16 + m];
#pragma unroll
        for (int c = 0; c < 8; ++c) acc[c] = fmaf(msk, (float)v[c], acc[c]);
    };

    int e = 0;
    for (; e + 4 < cnt; e += 8) { pack(e); pack(e + 4); }
    if (e < cnt) pack(e);

#pragma unroll
    for (int c = 0; c < 8; ++c) {
        acc[c] += __shfl_xor(acc[c], 16);
        acc[c] += __shfl_xor(acc[c], 32);
    }

    if (g == 0) {
        float4 cb = combo[w];
        f16x8 hw = hp[(size_t)w * 16 + m];
        f16x8 h0v = ((const f16x8*)h0_16)[(size_t)w * 16 + m];
        f16x8 o;
#pragma unroll
        for (int c = 0; c < 8; ++c) {
            float v = cb.y * acc[c] + cb.z * (float)hw[c] + 0.1f * (float)h0v[c];
            o[c] = (f16)v;
        }
        ((f16x8*)p16)[(size_t)w * 16 + m] = o;
    }
}

// ---------------- fp16 MFMA GEMM: act(A @ W), writes scaled hs (and h0 for mode 0) ----------------
// mode 0: v = relu(acc + b); h0_out[row] = v; hs_out[row] = dis[row]*v
// mode 1: v = max(acc, sb);  hs_out[row] = dis[row]*v
#define WT_OFF 16384

__global__ __launch_bounds__(256, 2) void gemm_mfma(
        const f16* __restrict__ A, const f16* __restrict__ Wt,
        const float* __restrict__ bvec, const float4* __restrict__ combo,
        f16* __restrict__ hs_out, f16* __restrict__ h0_out, int mode) {
    __shared__ uint4 smem4[3072];                // 48 KiB: A 16K | Wt 32K
    char* smem = (char*)smem4;
    int tid = threadIdx.x;
    int r0 = blockIdx.x * 64;

    const uint4* Asrc = (const uint4*)A;
    for (int c = tid; c < 1024; c += 256) {
        int row = c >> 4, q = c & 15;
        int grow = r0 + row; if (grow >= N_NODES) grow = N_NODES - 1;
        uint4 v = Asrc[(size_t)grow * 16 + q];
        *(uint4*)&smem[row * 256 + ((q * 16) ^ ((row & 7) << 4))] = v;
    }
    const uint4* Wsrc = (const uint4*)Wt;
    for (int c = tid; c < 2048; c += 256) {
        int n = c >> 4, q = c & 15;
        uint4 v = Wsrc[n * 16 + q];
        *(uint4*)&smem[WT_OFF + n * 256 + ((q * 16) ^ ((n & 7) << 4))] = v;
    }
    __syncthreads();

    int l = tid & 63, w = tid >> 6;
    int wr = w >> 1, wc = w & 1;
    int lg = l >> 4, lm = l & 15;

    union F8 { f16x8 v8; struct { f16x4 lo, hi; } p; };
    f32x4 acc[2][4];
#pragma unroll
    for (int m = 0; m < 2; ++m)
#pragma unroll
        for (int j = 0; j < 4; ++j) acc[m][j] = (f32x4){0.f, 0.f, 0.f, 0.f};

#pragma unroll
    for (int kk = 0; kk < 4; ++kk) {
        int boff = kk * 64 + lg * 8;
        F8 a[2], b[4];
#pragma unroll
        for (int m = 0; m < 2; ++m) {
            int row = wr * 32 + m * 16 + lm;
            int swz = (row & 7) << 4;
            int rb = row * 256;
            a[m].p.lo = *(const f16x4*)&smem[rb + (boff ^ swz)];
            a[m].p.hi = *(const f16x4*)&smem[rb + ((boff + 32) ^ swz)];
        }
#pragma unroll
        for (int j = 0; j < 4; ++j) {
            int n = wc * 64 + j * 16 + lm;
            int swz = (n & 7) << 4;
            int nb = WT_OFF + n * 256;
            b[j].p.lo = *(const f16x4*)&smem[nb + (boff ^ swz)];
            b[j].p.hi = *(const f16x4*)&smem[nb + ((boff + 32) ^ swz)];
        }
#pragma unroll
        for (int m = 0; m < 2; ++m)
#pragma unroll
            for (int j = 0; j < 4; ++j)
                acc[m][j] = __builtin_amdgcn_mfma_f32_16x16x32_f16(a[m].v8, b[j].v8, acc[m][j], 0, 0, 0);
    }

#pragma unroll
    for (int m = 0; m < 2; ++m) {
#pragma unroll
        for (int r = 0; r < 4; ++r) {
            int row = r0 + wr * 32 + m * 16 + lg * 4 + r;
            if (row < N_NODES) {
                float dis = combo[row].x;
#pragma unroll
                for (int j = 0; j < 4; ++j) {
                    int col = wc * 64 + j * 16 + lm;
                    float bias = bvec[col];
                    float v = acc[m][j][r];
                    v = mode ? fmaxf(v, bias) : fmaxf(v + bias, 0.f);
                    if (mode == 0) h0_out[(size_t)row * HDIM + col] = (f16)v;
                    hs_out[(size_t)row * HDIM + col] = (f16)(dis * v);
                }
            }
        }
    }
}

// ---------------- output layer via MFMA: out = (hs/dis) @ W_out + b_out ----------------
#define WOT_OFF 16384   // A tile 64*256B

__global__ __launch_bounds__(256) void out_mfma(
        const f16* __restrict__ A, const f16* __restrict__ Wot,
        const float* __restrict__ bo, const float4* __restrict__ combo,
        float* __restrict__ out) {
    __shared__ uint4 smem4[1792];                // 28 KiB: A 16K | Wot 12K
    char* smem = (char*)smem4;
    int tid = threadIdx.x;
    int r0 = blockIdx.x * 64;

    const uint4* Asrc = (const uint4*)A;
    for (int c = tid; c < 1024; c += 256) {
        int row = c >> 4, q = c & 15;
        int grow = r0 + row; if (grow >= N_NODES) grow = N_NODES - 1;
        uint4 v = Asrc[(size_t)grow * 16 + q];
        *(uint4*)&smem[row * 256 + ((q * 16) ^ ((row & 7) << 4))] = v;
    }
    const uint4* Wsrc = (const uint4*)Wot;
    for (int c = tid; c < 768; c += 256) {
        int n = c >> 4, q = c & 15;
        uint4 v = Wsrc[n * 16 + q];
        *(uint4*)&smem[WOT_OFF + n * 256 + ((q * 16) ^ ((n & 7) << 4))] = v;
    }
    __syncthreads();

    int l = tid & 63, w = tid >> 6;
    int lg = l >> 4, lm = l & 15;

    union F8 { f16x8 v8; struct { f16x4 lo, hi; } p; };
    f32x4 acc[3];
#pragma unroll
    for (int j = 0; j < 3; ++j) acc[j] = (f32x4){0.f, 0.f, 0.f, 0.f};

#pragma unroll
    for (int kk = 0; kk < 4; ++kk) {
        int boff = kk * 64 + lg * 8;
        F8 a, b[3];
        int row = w * 16 + lm;
        int swz = (row & 7) << 4;
        int rb = row * 256;
        a.p.lo = *(const f16x4*)&smem[rb + (boff ^ swz)];
        a.p.hi = *(const f16x4*)&smem[rb + ((boff + 32) ^ swz)];
#pragma unroll
        for (int j = 0; j < 3; ++j) {
            int n = j * 16 + lm;
            int swz2 = (n & 7) << 4;
            int nb = WOT_OFF + n * 256;
            b[j].p.lo = *(const f16x4*)&smem[nb + (boff ^ swz2)];
            b[j].p.hi = *(const f16x4*)&smem[nb + ((boff + 32) ^ swz2)];
        }
#pragma unroll
        for (int j = 0; j < 3; ++j)
            acc[j] = __builtin_amdgcn_mfma_f32_16x16x32_f16(a.v8, b[j].v8, acc[j], 0, 0, 0);
    }

#pragma unroll
    for (int r = 0; r < 4; ++r) {
        int row = r0 + w * 16 + lg * 4 + r;
        if (row < N_NODES) {
            float g2 = combo[row].w;      // 1/dis: un-scale the hs row
#pragma unroll
            for (int j = 0; j < 3; ++j) {
                int col = j * 16 + lm;
                if (col < N_CLASSES)
                    out[(size_t)row * N_CLASSES + col] = g2 * acc[j][r] + bo[col];
            }
        }
    }
}

// ---------------- launch ----------------

extern "C" void kernel_launch(void* const* d_in, const int* in_sizes, int n_in,
                              void* d_out, int out_size, void* d_ws, size_t ws_size,
                              hipStream_t stream) {
    const float* x       = (const float*)d_in[0];
    const int*   ei      = (const int*)d_in[1];
    const float* W_in    = (const float*)d_in[2];
    const float* b_in    = (const float*)d_in[3];
    const float* gcn_W   = (const float*)d_in[4];
    const float* srelu_b = (const float*)d_in[5];
    const float* W_out   = (const float*)d_in[6];
    const float* b_out   = (const float*)d_in[7];
    float* outp = (float*)d_out;

    char* ws = (char*)d_ws;
    size_t off = 0;
    auto alloc = [&](size_t bytes) -> void* {
        void* p = ws + off;
        off += (bytes + 255) & ~(size_t)255;
        return p;
    };
    int*    deg_cnt = (int*)alloc((size_t)N_NODES * 4);
    int*    col_cnt = (int*)alloc((size_t)N_NODES * 4);
    float4* combo   = (float4*)alloc((size_t)N_NODES * 16);
    unsigned short* e_slot = (unsigned short*)alloc((size_t)N_NODES * CAP * 2);
    f16*    wt16    = (f16*)alloc((size_t)9 * HDIM * HDIM * 2);
    f16*    wot16   = (f16*)alloc((size_t)48 * HDIM * 2);
    f16*    x16     = (f16*)alloc((size_t)N_NODES * HDIM * 2);
    f16*    h0_16   = (f16*)alloc((size_t)N_NODES * HDIM * 2);
    f16*    hs0     = (f16*)alloc((size_t)N_NODES * HDIM * 2);
    f16*    hsA     = (f16*)alloc((size_t)N_NODES * HDIM * 2);
    f16*    hsB     = (f16*)alloc((size_t)N_NODES * HDIM * 2);
    f16*    p16     = (f16*)alloc((size_t)N_NODES * HDIM * 2);

    hipMemsetAsync(deg_cnt, 0, (size_t)N_NODES * 4, stream);
    hipMemsetAsync(col_cnt, 0, (size_t)N_NODES * 4, stream);

    setup_kernel<<<BUILD_BLOCKS + CONV_BLOCKS + PREP_BLOCKS, 256, 0, stream>>>(
        ei, x, W_in, gcn_W, W_out, deg_cnt, col_cnt, e_slot, x16, wt16, wot16);
    combo_kernel<<<(N_NODES + 255) / 256, 256, 0, stream>>>(deg_cnt, combo);

    // input layer: h0 = relu(x @ W_in + b_in); hs0 = dis*h0
    gemm_mfma<<<(N_NODES + 63) / 64, 256, 0, stream>>>(
        x16, wt16, b_in, combo, hs0, h0_16, 0);

    const f16* hcur = hs0;
    for (int l = 0; l < N_LAYERS; ++l) {
        f16* hnext = (l & 1) ? hsB : hsA;
        agg_combine<<<(N_NODES * 64 + 255) / 256, 256, 0, stream>>>(
            hcur, h0_16, col_cnt, e_slot, combo, p16);
        gemm_mfma<<<(N_NODES + 63) / 64, 256, 0, stream>>>(
            p16, wt16 + (size_t)(l + 1) * HDIM * HDIM,
            srelu_b + (size_t)l * HDIM, combo, hnext, nullptr, 1);
        hcur = hnext;
    }

    out_mfma<<<(N_NODES + 63) / 64, 256, 0, stream>>>(hcur, wot16, b_out, combo, outp);
}

// Round 10
// 773.184 us; speedup vs baseline: 2.3117x; 1.1566x over previous
//
#include <hip/hip_runtime.h>

#define N_NODES 50000
#define N_EDGES 1600000
#define HDIM 128
#define N_CLASSES 40
#define N_LAYERS 8
#define CAP 128                 // max stored in-degree; Poisson(32): P(>128) ~ 1e-19/node

#define BUILD_BLOCKS 782        // ceil(1.6M/8/256)
#define CONV_BLOCKS  3125       // 50000*128/8/256
#define PREP_BLOCKS   600       // 9*16384/256 (=576) + 48*128/256 (=24)

typedef _Float16 f16;
typedef _Float16 f16x2 __attribute__((ext_vector_type(2)));
typedef _Float16 f16x4 __attribute__((ext_vector_type(4)));
typedef _Float16 f16x8 __attribute__((ext_vector_type(8)));
typedef float f32x4 __attribute__((ext_vector_type(4)));
typedef int i32x4 __attribute__((ext_vector_type(4)));

__device__ __forceinline__ int clamp_idx(int v) {
    v = v < 0 ? 0 : v;
    return v >= N_NODES ? N_NODES - 1 : v;
}

// ---------------- fused setup: CSR build (u16 slots, 8 edges/thread) + x->fp16 + weight prep ----------------

__global__ __launch_bounds__(256) void setup_kernel(
        const int* __restrict__ ei, const float* __restrict__ x,
        const float* __restrict__ W_in, const float* __restrict__ gcn_W,
        const float* __restrict__ W_out,
        int* __restrict__ deg_cnt, int* __restrict__ col_cnt,
        unsigned short* __restrict__ e_slot,
        f16* __restrict__ x16, f16* __restrict__ wt, f16* __restrict__ wot) {
    int b = blockIdx.x;
    if (b < BUILD_BLOCKS) {
        int t = b * 256 + threadIdx.x;          // 8 edges per thread: 16 atomics in flight
        if (t < N_EDGES / 8) {
            i32x4 ra = ((const i32x4*)ei)[2 * t];
            i32x4 rb = ((const i32x4*)ei)[2 * t + 1];
            i32x4 ca = ((const i32x4*)(ei + N_EDGES))[2 * t];
            i32x4 cb = ((const i32x4*)(ei + N_EDGES))[2 * t + 1];
            int rs[8] = {ra[0], ra[1], ra[2], ra[3], rb[0], rb[1], rb[2], rb[3]};
            int cs[8] = {ca[0], ca[1], ca[2], ca[3], cb[0], cb[1], cb[2], cb[3]};
#pragma unroll
            for (int i = 0; i < 8; ++i) {
                int r = clamp_idx(rs[i]);
                int c = clamp_idx(cs[i]);
                if (r != c) {
                    atomicAdd(&deg_cnt[r], 1);               // fire-and-forget
                    int s = atomicAdd(&col_cnt[c], 1);       // slot
                    if (s < CAP) e_slot[(size_t)c * CAP + s] = (unsigned short)r;
                }
            }
        }
    } else if (b < BUILD_BLOCKS + CONV_BLOCKS) {
        int i = (b - BUILD_BLOCKS) * 256 + threadIdx.x;      // group of 8 floats
        if (i < N_NODES * HDIM / 8) {
            const float4* xs = (const float4*)x;
            float4 v0 = xs[2 * i], v1 = xs[2 * i + 1];
            f16x8 o;
            o[0] = (f16)v0.x; o[1] = (f16)v0.y; o[2] = (f16)v0.z; o[3] = (f16)v0.w;
            o[4] = (f16)v1.x; o[5] = (f16)v1.y; o[6] = (f16)v1.z; o[7] = (f16)v1.w;
            ((f16x8*)x16)[i] = o;
        }
    } else {
        int idx = (b - BUILD_BLOCKS - CONV_BLOCKS) * 256 + threadIdx.x;
        if (idx < 9 * HDIM * HDIM) {
            // W_in + gcn_W -> fp16, transposed: wt[mat][n][k]
            int mat = idx >> 14;
            int rem = idx & 16383;
            int k = rem >> 7, n = rem & 127;
            float v = (mat == 0) ? W_in[rem] : gcn_W[(mat - 1) * 16384 + rem];
            wt[mat * 16384 + n * 128 + k] = (f16)v;
        } else {
            int j = idx - 9 * HDIM * HDIM;                   // 0..6143
            if (j < 48 * 128) {
                int n = j >> 7, k = j & 127;                 // wot[n][k], pad n>=40
                wot[n * 128 + k] = (n < N_CLASSES) ? (f16)W_out[k * N_CLASSES + n] : (f16)0.f;
            }
        }
    }
}

// per-node constants: combo = {dis, 0.8*dis, (0.8/deg+0.1)*sqrt(deg), sqrt(deg)}
__global__ void combo_kernel(const int* __restrict__ deg_cnt, float4* __restrict__ combo) {
    int i = blockIdx.x * blockDim.x + threadIdx.x;
    if (i >= N_NODES) return;
    float d = (float)(deg_cnt[i] + 1);   // includes self loop, >= 1
    float dis = rsqrtf(d);
    float g = sqrtf(d);                  // 1/dis
    combo[i] = make_float4(dis, 0.8f * dis, (0.8f / d + 0.1f) * g, g);
}

// ---------------- aggregation + residual combine ----------------
// One wave per node. Lane owns f16x2 (4B) of the 256B row: one gather
// instruction = one edge's contiguous row (coalescing-friendly; round-9's
// 4-edges/instr shape measured slower). 8 independent gathers in flight.
// hs rows pre-scaled by dis[r]: inner loop is a pure sum.

__global__ __launch_bounds__(256) void agg_combine(
        const f16* __restrict__ hs, const f16* __restrict__ h0_16,
        const int* __restrict__ col_cnt, const unsigned short* __restrict__ e_slot,
        const float4* __restrict__ combo, f16* __restrict__ p16) {
    int w = (blockIdx.x * blockDim.x + threadIdx.x) >> 6;
    int lane = threadIdx.x & 63;
    if (w >= N_NODES) return;
    int cnt = col_cnt[w]; if (cnt > CAP) cnt = CAP;
    const f16x2* hp = (const f16x2*)hs;                 // row = node*64 + lane
    const unsigned short* slots = e_slot + (size_t)w * CAP;
    float ax = 0.f, ay = 0.f;
    int e = 0;
    for (; e + 8 <= cnt; e += 8) {
        ushort4 sa = *(const ushort4*)(slots + e);      // wave-uniform 8B loads
        ushort4 sb = *(const ushort4*)(slots + e + 4);
        f16x2 v0 = hp[(size_t)sa.x * 64 + lane];
        f16x2 v1 = hp[(size_t)sa.y * 64 + lane];
        f16x2 v2 = hp[(size_t)sa.z * 64 + lane];
        f16x2 v3 = hp[(size_t)sa.w * 64 + lane];
        f16x2 v4 = hp[(size_t)sb.x * 64 + lane];
        f16x2 v5 = hp[(size_t)sb.y * 64 + lane];
        f16x2 v6 = hp[(size_t)sb.z * 64 + lane];
        f16x2 v7 = hp[(size_t)sb.w * 64 + lane];
        ax += (float)v0[0] + (float)v1[0] + (float)v2[0] + (float)v3[0]
            + (float)v4[0] + (float)v5[0] + (float)v6[0] + (float)v7[0];
        ay += (float)v0[1] + (float)v1[1] + (float)v2[1] + (float)v3[1]
            + (float)v4[1] + (float)v5[1] + (float)v6[1] + (float)v7[1];
    }
    for (; e + 4 <= cnt; e += 4) {
        ushort4 s4 = *(const ushort4*)(slots + e);
        f16x2 v0 = hp[(size_t)s4.x * 64 + lane];
        f16x2 v1 = hp[(size_t)s4.y * 64 + lane];
        f16x2 v2 = hp[(size_t)s4.z * 64 + lane];
        f16x2 v3 = hp[(size_t)s4.w * 64 + lane];
        ax += (float)v0[0] + (float)v1[0] + (float)v2[0] + (float)v3[0];
        ay += (float)v0[1] + (float)v1[1] + (float)v2[1] + (float)v3[1];
    }
    for (; e < cnt; ++e) {
        int r = slots[e];
        f16x2 v = hp[(size_t)r * 64 + lane];
        ax += (float)v[0];
        ay += (float)v[1];
    }
    float4 cb = combo[w];
    f16x2 hw = hp[(size_t)w * 64 + lane];
    f16x2 h0v = ((const f16x2*)h0_16)[(size_t)w * 64 + lane];
    float px = cb.y * ax + cb.z * (float)hw[0] + 0.1f * (float)h0v[0];
    float py = cb.y * ay + cb.z * (float)hw[1] + 0.1f * (float)h0v[1];
    f16x2 o; o[0] = (f16)px; o[1] = (f16)py;
    ((f16x2*)p16)[(size_t)w * 64 + lane] = o;
}

// ---------------- fp16 MFMA GEMM: act(A @ W), writes scaled hs (and h0 for mode 0) ----------------
// mode 0: v = relu(acc + b); h0_out[row] = v; hs_out[row] = dis[row]*v
// mode 1: v = max(acc, sb);  hs_out[row] = dis[row]*v
#define WT_OFF 16384

__global__ __launch_bounds__(256, 2) void gemm_mfma(
        const f16* __restrict__ A, const f16* __restrict__ Wt,
        const float* __restrict__ bvec, const float4* __restrict__ combo,
        f16* __restrict__ hs_out, f16* __restrict__ h0_out, int mode) {
    __shared__ uint4 smem4[3072];                // 48 KiB: A 16K | Wt 32K
    char* smem = (char*)smem4;
    int tid = threadIdx.x;
    int r0 = blockIdx.x * 64;

    const uint4* Asrc = (const uint4*)A;
    for (int c = tid; c < 1024; c += 256) {
        int row = c >> 4, q = c & 15;
        int grow = r0 + row; if (grow >= N_NODES) grow = N_NODES - 1;
        uint4 v = Asrc[(size_t)grow * 16 + q];
        *(uint4*)&smem[row * 256 + ((q * 16) ^ ((row & 7) << 4))] = v;
    }
    const uint4* Wsrc = (const uint4*)Wt;
    for (int c = tid; c < 2048; c += 256) {
        int n = c >> 4, q = c & 15;
        uint4 v = Wsrc[n * 16 + q];
        *(uint4*)&smem[WT_OFF + n * 256 + ((q * 16) ^ ((n & 7) << 4))] = v;
    }
    __syncthreads();

    int l = tid & 63, w = tid >> 6;
    int wr = w >> 1, wc = w & 1;
    int lg = l >> 4, lm = l & 15;

    union F8 { f16x8 v8; struct { f16x4 lo, hi; } p; };
    f32x4 acc[2][4];
#pragma unroll
    for (int m = 0; m < 2; ++m)
#pragma unroll
        for (int j = 0; j < 4; ++j) acc[m][j] = (f32x4){0.f, 0.f, 0.f, 0.f};

#pragma unroll
    for (int kk = 0; kk < 4; ++kk) {
        int boff = kk * 64 + lg * 8;
        F8 a[2], b[4];
#pragma unroll
        for (int m = 0; m < 2; ++m) {
            int row = wr * 32 + m * 16 + lm;
            int swz = (row & 7) << 4;
            int rb = row * 256;
            a[m].p.lo = *(const f16x4*)&smem[rb + (boff ^ swz)];
            a[m].p.hi = *(const f16x4*)&smem[rb + ((boff + 32) ^ swz)];
        }
#pragma unroll
        for (int j = 0; j < 4; ++j) {
            int n = wc * 64 + j * 16 + lm;
            int swz = (n & 7) << 4;
            int nb = WT_OFF + n * 256;
            b[j].p.lo = *(const f16x4*)&smem[nb + (boff ^ swz)];
            b[j].p.hi = *(const f16x4*)&smem[nb + ((boff + 32) ^ swz)];
        }
#pragma unroll
        for (int m = 0; m < 2; ++m)
#pragma unroll
            for (int j = 0; j < 4; ++j)
                acc[m][j] = __builtin_amdgcn_mfma_f32_16x16x32_f16(a[m].v8, b[j].v8, acc[m][j], 0, 0, 0);
    }

#pragma unroll
    for (int m = 0; m < 2; ++m) {
#pragma unroll
        for (int r = 0; r < 4; ++r) {
            int row = r0 + wr * 32 + m * 16 + lg * 4 + r;
            if (row < N_NODES) {
                float dis = combo[row].x;
#pragma unroll
                for (int j = 0; j < 4; ++j) {
                    int col = wc * 64 + j * 16 + lm;
                    float bias = bvec[col];
                    float v = acc[m][j][r];
                    v = mode ? fmaxf(v, bias) : fmaxf(v + bias, 0.f);
                    if (mode == 0) h0_out[(size_t)row * HDIM + col] = (f16)v;
                    hs_out[(size_t)row * HDIM + col] = (f16)(dis * v);
                }
            }
        }
    }
}

// ---------------- output layer via MFMA: out = (hs/dis) @ W_out + b_out ----------------
#define WOT_OFF 16384   // A tile 64*256B

__global__ __launch_bounds__(256) void out_mfma(
        const f16* __restrict__ A, const f16* __restrict__ Wot,
        const float* __restrict__ bo, const float4* __restrict__ combo,
        float* __restrict__ out) {
    __shared__ uint4 smem4[1792];                // 28 KiB: A 16K | Wot 12K
    char* smem = (char*)smem4;
    int tid = threadIdx.x;
    int r0 = blockIdx.x * 64;

    const uint4* Asrc = (const uint4*)A;
    for (int c = tid; c < 1024; c += 256) {
        int row = c >> 4, q = c & 15;
        int grow = r0 + row; if (grow >= N_NODES) grow = N_NODES - 1;
        uint4 v = Asrc[(size_t)grow * 16 + q];
        *(uint4*)&smem[row * 256 + ((q * 16) ^ ((row & 7) << 4))] = v;
    }
    const uint4* Wsrc = (const uint4*)Wot;
    for (int c = tid; c < 768; c += 256) {
        int n = c >> 4, q = c & 15;
        uint4 v = Wsrc[n * 16 + q];
        *(uint4*)&smem[WOT_OFF + n * 256 + ((q * 16) ^ ((n & 7) << 4))] = v;
    }
    __syncthreads();

    int l = tid & 63, w = tid >> 6;
    int lg = l >> 4, lm = l & 15;

    union F8 { f16x8 v8; struct { f16x4 lo, hi; } p; };
    f32x4 acc[3];
#pragma unroll
    for (int j = 0; j < 3; ++j) acc[j] = (f32x4){0.f, 0.f, 0.f, 0.f};

#pragma unroll
    for (int kk = 0; kk < 4; ++kk) {
        int boff = kk * 64 + lg * 8;
        F8 a, b[3];
        int row = w * 16 + lm;
        int swz = (row & 7) << 4;
        int rb = row * 256;
        a.p.lo = *(const f16x4*)&smem[rb + (boff ^ swz)];
        a.p.hi = *(const f16x4*)&smem[rb + ((boff + 32) ^ swz)];
#pragma unroll
        for (int j = 0; j < 3; ++j) {
            int n = j * 16 + lm;
            int swz2 = (n & 7) << 4;
            int nb = WOT_OFF + n * 256;
            b[j].p.lo = *(const f16x4*)&smem[nb + (boff ^ swz2)];
            b[j].p.hi = *(const f16x4*)&smem[nb + ((boff + 32) ^ swz2)];
        }
#pragma unroll
        for (int j = 0; j < 3; ++j)
            acc[j] = __builtin_amdgcn_mfma_f32_16x16x32_f16(a.v8, b[j].v8, acc[j], 0, 0, 0);
    }

#pragma unroll
    for (int r = 0; r < 4; ++r) {
        int row = r0 + w * 16 + lg * 4 + r;
        if (row < N_NODES) {
            float g2 = combo[row].w;      // 1/dis: un-scale the hs row
#pragma unroll
            for (int j = 0; j < 3; ++j) {
                int col = j * 16 + lm;
                if (col < N_CLASSES)
                    out[(size_t)row * N_CLASSES + col] = g2 * acc[j][r] + bo[col];
            }
        }
    }
}

// ---------------- launch ----------------

extern "C" void kernel_launch(void* const* d_in, const int* in_sizes, int n_in,
                              void* d_out, int out_size, void* d_ws, size_t ws_size,
                              hipStream_t stream) {
    const float* x       = (const float*)d_in[0];
    const int*   ei      = (const int*)d_in[1];
    const float* W_in    = (const float*)d_in[2];
    const float* b_in    = (const float*)d_in[3];
    const float* gcn_W   = (const float*)d_in[4];
    const float* srelu_b = (const float*)d_in[5];
    const float* W_out   = (const float*)d_in[6];
    const float* b_out   = (const float*)d_in[7];
    float* outp = (float*)d_out;

    char* ws = (char*)d_ws;
    size_t off = 0;
    auto alloc = [&](size_t bytes) -> void* {
        void* p = ws + off;
        off += (bytes + 255) & ~(size_t)255;
        return p;
    };
    int*    deg_cnt = (int*)alloc((size_t)N_NODES * 4);
    int*    col_cnt = (int*)alloc((size_t)N_NODES * 4);
    float4* combo   = (float4*)alloc((size_t)N_NODES * 16);
    unsigned short* e_slot = (unsigned short*)alloc((size_t)N_NODES * CAP * 2);
    f16*    wt16    = (f16*)alloc((size_t)9 * HDIM * HDIM * 2);
    f16*    wot16   = (f16*)alloc((size_t)48 * HDIM * 2);
    f16*    x16     = (f16*)alloc((size_t)N_NODES * HDIM * 2);
    f16*    h0_16   = (f16*)alloc((size_t)N_NODES * HDIM * 2);
    f16*    hs0     = (f16*)alloc((size_t)N_NODES * HDIM * 2);
    f16*    hsA     = (f16*)alloc((size_t)N_NODES * HDIM * 2);
    f16*    hsB     = (f16*)alloc((size_t)N_NODES * HDIM * 2);
    f16*    p16     = (f16*)alloc((size_t)N_NODES * HDIM * 2);

    hipMemsetAsync(deg_cnt, 0, (size_t)N_NODES * 4, stream);
    hipMemsetAsync(col_cnt, 0, (size_t)N_NODES * 4, stream);

    setup_kernel<<<BUILD_BLOCKS + CONV_BLOCKS + PREP_BLOCKS, 256, 0, stream>>>(
        ei, x, W_in, gcn_W, W_out, deg_cnt, col_cnt, e_slot, x16, wt16, wot16);
    combo_kernel<<<(N_NODES + 255) / 256, 256, 0, stream>>>(deg_cnt, combo);

    // input layer: h0 = relu(x @ W_in + b_in); hs0 = dis*h0
    gemm_mfma<<<(N_NODES + 63) / 64, 256, 0, stream>>>(
        x16, wt16, b_in, combo, hs0, h0_16, 0);

    const f16* hcur = hs0;
    for (int l = 0; l < N_LAYERS; ++l) {
        f16* hnext = (l & 1) ? hsB : hsA;
        agg_combine<<<(N_NODES * 64 + 255) / 256, 256, 0, stream>>>(
            hcur, h0_16, col_cnt, e_slot, combo, p16);
        gemm_mfma<<<(N_NODES + 63) / 64, 256, 0, stream>>>(
            p16, wt16 + (size_t)(l + 1) * HDIM * HDIM,
            srelu_b + (size_t)l * HDIM, combo, hnext, nullptr, 1);
        hcur = hnext;
    }

    out_mfma<<<(N_NODES + 63) / 64, 256, 0, stream>>>(hcur, wot16, b_out, combo, outp);
}